// Round 1
// baseline (379.098 us; speedup 1.0000x reference)
//
#include <hip/hip_runtime.h>
#include <hip/hip_bf16.h>
#include <stdint.h>

// Problem sizes (fixed by reference)
#define BT     8
#define T_SEQ  4096
#define K_F    512
#define N_H    1024
#define M_TOT  (BT * T_SEQ)   // 32768
#define NLAYER 4

typedef short  bf16x8 __attribute__((ext_vector_type(8)));
typedef float  f32x4  __attribute__((ext_vector_type(4)));
typedef ushort u16x8  __attribute__((ext_vector_type(8)));

// f32 -> bf16 (round-to-nearest-even), bit-level (no hip_bf16 API dependence)
__device__ __forceinline__ ushort f2bf(float f) {
  uint32_t u = __builtin_bit_cast(uint32_t, f);
  u += 0x7fffu + ((u >> 16) & 1u);
  return (ushort)(u >> 16);
}

// ---------------- x: f32 -> bf16, 8 elems/thread ----------------
__global__ __launch_bounds__(256) void cvt_x_kernel(const float* __restrict__ x,
                                                    ushort* __restrict__ xb) {
  const int i = blockIdx.x * 256 + threadIdx.x;  // 0 .. 2097151 (exact grid)
  const float4* xv = (const float4*)x;
  float4 v0 = xv[2 * i + 0];
  float4 v1 = xv[2 * i + 1];
  u16x8 o;
  o[0] = f2bf(v0.x); o[1] = f2bf(v0.y); o[2] = f2bf(v0.z); o[3] = f2bf(v0.w);
  o[4] = f2bf(v1.x); o[5] = f2bf(v1.y); o[6] = f2bf(v1.z); o[7] = f2bf(v1.w);
  *((u16x8*)xb + i) = o;
}

// ---------------- W [K][N] f32 -> Wt [N][K] bf16 (LDS tile transpose) -------
__global__ __launch_bounds__(256) void trans_w_kernel(const float* __restrict__ W,
                                                      ushort* __restrict__ Wt) {
  __shared__ float tile[32][33];
  const int lx = threadIdx.x & 31;
  const int ly = threadIdx.x >> 5;  // 0..7
  const int k0 = blockIdx.x * 32;   // K tiles: 16
  const int n0 = blockIdx.y * 32;   // N tiles: 32
#pragma unroll
  for (int j = 0; j < 32; j += 8)
    tile[ly + j][lx] = W[(size_t)(k0 + ly + j) * N_H + n0 + lx];
  __syncthreads();
#pragma unroll
  for (int j = 0; j < 32; j += 8)
    Wt[(size_t)(n0 + ly + j) * K_F + k0 + lx] = f2bf(tile[lx][ly + j]);
}

// ---------------- GEMM: Y[M][N] = Xb[M][K] * Wt[N][K]^T + bias --------------
// 128x128 tile, BK=32, 4 waves (2x2), mfma_f32_16x16x32_bf16.
// Fragment layouts (measured, learn_hip m89/m91/m92):
//   A: row = lane&15, k = (lane>>4)*8 + i (contiguous bf16x8)
//   B: col = lane&15, k = (lane>>4)*8 + i
//   D: col = lane&15, row = (lane>>4)*4 + reg
#define BM 128
#define BN 128
#define BKK 32

__global__ __launch_bounds__(256) void gemm_kernel(const ushort* __restrict__ Xb,
                                                   const ushort* __restrict__ Wt,
                                                   const float* __restrict__ bias,
                                                   float* __restrict__ Y) {
  __shared__ ushort lsA[BM * BKK];
  __shared__ ushort lsB[BN * BKK];
  const int tid  = threadIdx.x;
  const int lane = tid & 63;
  const int wv   = tid >> 6;
  const int wr   = wv >> 1;      // wave row (0..1) -> 64 rows
  const int wc   = wv & 1;       // wave col (0..1) -> 64 cols
  const int m0   = blockIdx.x * BM;
  const int n0   = blockIdx.y * BN;

  // staging: each thread owns 16 ushorts of each tile (row = tid/2, half-row)
  const int srow = tid >> 1;
  const int scol = (tid & 1) * 16;
  const ushort* gA = Xb + (size_t)(m0 + srow) * K_F + scol;
  const ushort* gB = Wt + (size_t)(n0 + srow) * K_F + scol;
  ushort* wA = &lsA[srow * BKK + scol];
  ushort* wB = &lsB[srow * BKK + scol];

  f32x4 acc[4][4];
#pragma unroll
  for (int i = 0; i < 4; i++)
#pragma unroll
    for (int j = 0; j < 4; j++) acc[i][j] = (f32x4)0.0f;

  const int lr = lane & 15;
  const int kg = (lane >> 4) * 8;

  for (int kt = 0; kt < K_F; kt += BKK) {
    bf16x8 ra0 = *(const bf16x8*)(gA + kt);
    bf16x8 ra1 = *(const bf16x8*)(gA + kt + 8);
    bf16x8 rb0 = *(const bf16x8*)(gB + kt);
    bf16x8 rb1 = *(const bf16x8*)(gB + kt + 8);
    __syncthreads();  // previous iter's ds_reads done before overwrite
    *(bf16x8*)(wA) = ra0;
    *(bf16x8*)(wA + 8) = ra1;
    *(bf16x8*)(wB) = rb0;
    *(bf16x8*)(wB + 8) = rb1;
    __syncthreads();
    bf16x8 af[4], bfr[4];
#pragma unroll
    for (int fm = 0; fm < 4; fm++)
      af[fm] = *(const bf16x8*)&lsA[(wr * 64 + fm * 16 + lr) * BKK + kg];
#pragma unroll
    for (int fn = 0; fn < 4; fn++)
      bfr[fn] = *(const bf16x8*)&lsB[(wc * 64 + fn * 16 + lr) * BKK + kg];
#pragma unroll
    for (int fm = 0; fm < 4; fm++)
#pragma unroll
      for (int fn = 0; fn < 4; fn++)
        acc[fm][fn] = __builtin_amdgcn_mfma_f32_16x16x32_bf16(af[fm], bfr[fn],
                                                              acc[fm][fn], 0, 0, 0);
  }

  // epilogue: D col = lane&15, row = (lane>>4)*4 + i ; add bias
#pragma unroll
  for (int fn = 0; fn < 4; fn++) {
    const int col = n0 + wc * 64 + fn * 16 + lr;
    const float bv = bias[col];
#pragma unroll
    for (int fm = 0; fm < 4; fm++) {
      const int row0 = m0 + wr * 64 + fm * 16 + (lane >> 4) * 4;
#pragma unroll
      for (int i = 0; i < 4; i++)
        Y[(size_t)(row0 + i) * N_H + col] = acc[fm][fn][i] + bv;
    }
  }
}

// ---------------- fused 4-layer diagonal SSM scan, in-place on Y ------------
// one thread per (b,h); 128 blocks x 64 threads
__global__ __launch_bounds__(64) void scan_kernel(float* __restrict__ Y,
                                                  const float* __restrict__ A,
                                                  const float* __restrict__ B,
                                                  const float* __restrict__ C,
                                                  const float* __restrict__ D) {
  const int b = blockIdx.x >> 4;
  const int h = ((blockIdx.x & 15) << 6) + threadIdx.x;

  float a0 = 1.f / (1.f + expf(-A[0 * N_H + h]));
  float a1 = 1.f / (1.f + expf(-A[1 * N_H + h]));
  float a2 = 1.f / (1.f + expf(-A[2 * N_H + h]));
  float a3 = 1.f / (1.f + expf(-A[3 * N_H + h]));
  float b0 = B[0 * N_H + h], b1 = B[1 * N_H + h], b2 = B[2 * N_H + h], b3 = B[3 * N_H + h];
  float c0 = C[0 * N_H + h], c1 = C[1 * N_H + h], c2 = C[2 * N_H + h], c3 = C[3 * N_H + h];
  float d0 = D[0 * N_H + h], d1 = D[1 * N_H + h], d2 = D[2 * N_H + h], d3 = D[3 * N_H + h];

  float* p = Y + (size_t)b * T_SEQ * N_H + h;
  float s0 = 0.f, s1 = 0.f, s2 = 0.f, s3 = 0.f;
#pragma unroll 8
  for (int t = 0; t < T_SEQ; t++) {
    float xv = p[(size_t)t * N_H];
    s0 = fmaf(a0, s0, b0 * xv); xv = fmaf(c0, s0, d0);
    s1 = fmaf(a1, s1, b1 * xv); xv = fmaf(c1, s1, d1);
    s2 = fmaf(a2, s2, b2 * xv); xv = fmaf(c2, s2, d2);
    s3 = fmaf(a3, s3, b3 * xv); xv = fmaf(c3, s3, d3);
    p[(size_t)t * N_H] = xv;
  }
}

extern "C" void kernel_launch(void* const* d_in, const int* in_sizes, int n_in,
                              void* d_out, int out_size, void* d_ws, size_t ws_size,
                              hipStream_t stream) {
  const float* x    = (const float*)d_in[0];
  const float* W    = (const float*)d_in[1];
  const float* b_in = (const float*)d_in[2];
  const float* A    = (const float*)d_in[3];
  const float* B    = (const float*)d_in[4];
  const float* C    = (const float*)d_in[5];
  const float* bias = (const float*)d_in[6];
  float* out = (float*)d_out;

  // workspace layout: xb [M_TOT*K_F] bf16 (32 MiB), Wt [N_H*K_F] bf16 (1 MiB)
  ushort* xb = (ushort*)d_ws;
  ushort* Wt = xb + (size_t)M_TOT * K_F;

  cvt_x_kernel<<<(M_TOT * K_F) / (256 * 8), 256, 0, stream>>>(x, xb);
  trans_w_kernel<<<dim3(K_F / 32, N_H / 32), 256, 0, stream>>>(W, Wt);
  gemm_kernel<<<dim3(M_TOT / BM, N_H / BN), 256, 0, stream>>>(xb, Wt, b_in, out);
  scan_kernel<<<BT * (N_H / 64), 64, 0, stream>>>(out, A, B, C, bias);
}

// Round 2
// 183.151 us; speedup vs baseline: 2.0699x; 2.0699x over previous
//
#include <hip/hip_runtime.h>
#include <hip/hip_bf16.h>
#include <stdint.h>

// Problem sizes (fixed by reference)
#define BT     8
#define T_SEQ  4096
#define K_F    512
#define N_H    1024
#define M_TOT  (BT * T_SEQ)   // 32768
#define NLAYER 4
#define LC     32             // chunk length for parallel scan
#define NC     (T_SEQ / LC)   // 128 chunks

typedef short  bf16x8 __attribute__((ext_vector_type(8)));
typedef float  f32x4  __attribute__((ext_vector_type(4)));
typedef ushort u16x8  __attribute__((ext_vector_type(8)));

// f32 -> bf16 (round-to-nearest-even)
__device__ __forceinline__ ushort f2bf(float f) {
  uint32_t u = __builtin_bit_cast(uint32_t, f);
  u += 0x7fffu + ((u >> 16) & 1u);
  return (ushort)(u >> 16);
}

// ---------------- x: f32 -> bf16, 8 elems/thread ----------------
__global__ __launch_bounds__(256) void cvt_x_kernel(const float* __restrict__ x,
                                                    ushort* __restrict__ xb) {
  const int i = blockIdx.x * 256 + threadIdx.x;
  const float4* xv = (const float4*)x;
  float4 v0 = xv[2 * i + 0];
  float4 v1 = xv[2 * i + 1];
  u16x8 o;
  o[0] = f2bf(v0.x); o[1] = f2bf(v0.y); o[2] = f2bf(v0.z); o[3] = f2bf(v0.w);
  o[4] = f2bf(v1.x); o[5] = f2bf(v1.y); o[6] = f2bf(v1.z); o[7] = f2bf(v1.w);
  *((u16x8*)xb + i) = o;
}

// ---------------- W [K][N] f32 -> Wt [N][K] bf16 ----------------
__global__ __launch_bounds__(256) void trans_w_kernel(const float* __restrict__ W,
                                                      ushort* __restrict__ Wt) {
  __shared__ float tile[32][33];
  const int lx = threadIdx.x & 31;
  const int ly = threadIdx.x >> 5;
  const int k0 = blockIdx.x * 32;
  const int n0 = blockIdx.y * 32;
#pragma unroll
  for (int j = 0; j < 32; j += 8)
    tile[ly + j][lx] = W[(size_t)(k0 + ly + j) * N_H + n0 + lx];
  __syncthreads();
#pragma unroll
  for (int j = 0; j < 32; j += 8)
    Wt[(size_t)(n0 + ly + j) * K_F + k0 + lx] = f2bf(tile[lx][ly + j]);
}

// ---------------- GEMM: Y[M][N] = Xb[M][K] * Wt[N][K]^T + bias --------------
#define BM 128
#define BN 128
#define BKK 32

__global__ __launch_bounds__(256) void gemm_kernel(const ushort* __restrict__ Xb,
                                                   const ushort* __restrict__ Wt,
                                                   const float* __restrict__ bias,
                                                   float* __restrict__ Y) {
  __shared__ ushort lsA[BM * BKK];
  __shared__ ushort lsB[BN * BKK];
  const int tid  = threadIdx.x;
  const int lane = tid & 63;
  const int wv   = tid >> 6;
  const int wr   = wv >> 1;
  const int wc   = wv & 1;
  const int m0   = blockIdx.x * BM;
  const int n0   = blockIdx.y * BN;

  const int srow = tid >> 1;
  const int scol = (tid & 1) * 16;
  const ushort* gA = Xb + (size_t)(m0 + srow) * K_F + scol;
  const ushort* gB = Wt + (size_t)(n0 + srow) * K_F + scol;
  ushort* wA = &lsA[srow * BKK + scol];
  ushort* wB = &lsB[srow * BKK + scol];

  f32x4 acc[4][4];
#pragma unroll
  for (int i = 0; i < 4; i++)
#pragma unroll
    for (int j = 0; j < 4; j++) acc[i][j] = (f32x4)0.0f;

  const int lr = lane & 15;
  const int kg = (lane >> 4) * 8;

  for (int kt = 0; kt < K_F; kt += BKK) {
    bf16x8 ra0 = *(const bf16x8*)(gA + kt);
    bf16x8 ra1 = *(const bf16x8*)(gA + kt + 8);
    bf16x8 rb0 = *(const bf16x8*)(gB + kt);
    bf16x8 rb1 = *(const bf16x8*)(gB + kt + 8);
    __syncthreads();
    *(bf16x8*)(wA) = ra0;
    *(bf16x8*)(wA + 8) = ra1;
    *(bf16x8*)(wB) = rb0;
    *(bf16x8*)(wB + 8) = rb1;
    __syncthreads();
    bf16x8 af[4], bfr[4];
#pragma unroll
    for (int fm = 0; fm < 4; fm++)
      af[fm] = *(const bf16x8*)&lsA[(wr * 64 + fm * 16 + lr) * BKK + kg];
#pragma unroll
    for (int fn = 0; fn < 4; fn++)
      bfr[fn] = *(const bf16x8*)&lsB[(wc * 64 + fn * 16 + lr) * BKK + kg];
#pragma unroll
    for (int fm = 0; fm < 4; fm++)
#pragma unroll
      for (int fn = 0; fn < 4; fn++)
        acc[fm][fn] = __builtin_amdgcn_mfma_f32_16x16x32_bf16(af[fm], bfr[fn],
                                                              acc[fm][fn], 0, 0, 0);
  }

#pragma unroll
  for (int fn = 0; fn < 4; fn++) {
    const int col = n0 + wc * 64 + fn * 16 + lr;
    const float bv = bias[col];
#pragma unroll
    for (int fm = 0; fm < 4; fm++) {
      const int row0 = m0 + wr * 64 + fm * 16 + (lane >> 4) * 4;
#pragma unroll
      for (int i = 0; i < 4; i++)
        Y[(size_t)(row0 + i) * N_H + col] = acc[fm][fn][i] + bv;
    }
  }
}

// ============ chunked parallel scan for the 4-layer diagonal SSM ============
// State per channel h: s = (s0,s1,s2,s3) (one per layer).
// s_t = M s_{t-1} + (input/bias terms),  M lower-triangular:
//   M[0][0]=a0; M[l][l]=a_l; M[l][j<l] = b_l*c_{l-1}*M[l-1][j].
// Pass A: per-(b,chunk) local recurrence from 0 -> end state E.
// Pass B: per-(b,h) serial combine over chunks with P=M^LC -> start states S.
// Pass C: per-(b,chunk) recurrence from exact S, write y.

// Pass A: one thread handles 4 channels (float4); grid = BT*NC blocks x 256
__global__ __launch_bounds__(256) void chunk_state_kernel(
    const float* __restrict__ Y, const float* __restrict__ A,
    const float* __restrict__ B, const float* __restrict__ C,
    const float* __restrict__ D, float* __restrict__ E) {
  const int b  = blockIdx.x / NC;
  const int c  = blockIdx.x % NC;
  const int h4 = threadIdx.x << 2;

  float a[4][4], bb[4][4], cc[4][4], dd[4][4];
#pragma unroll
  for (int l = 0; l < 4; l++) {
    f32x4 av = *(const f32x4*)(A + l * N_H + h4);
    f32x4 bv = *(const f32x4*)(B + l * N_H + h4);
    f32x4 cv = *(const f32x4*)(C + l * N_H + h4);
    f32x4 dv = *(const f32x4*)(D + l * N_H + h4);
#pragma unroll
    for (int ch = 0; ch < 4; ch++) {
      a[l][ch]  = 1.f / (1.f + __expf(-av[ch]));
      bb[l][ch] = bv[ch]; cc[l][ch] = cv[ch]; dd[l][ch] = dv[ch];
    }
  }

  float s[4][4] = {};
  const f32x4* yp = (const f32x4*)(Y + ((size_t)b * T_SEQ + (size_t)c * LC) * N_H) +
                    (h4 >> 2);
#pragma unroll 4
  for (int t = 0; t < LC; t++) {
    f32x4 xv = yp[(size_t)t * (N_H / 4)];
#pragma unroll
    for (int ch = 0; ch < 4; ch++) {
      float x = xv[ch];
#pragma unroll
      for (int l = 0; l < 4; l++) {
        s[l][ch] = fmaf(a[l][ch], s[l][ch], bb[l][ch] * x);
        x = fmaf(cc[l][ch], s[l][ch], dd[l][ch]);
      }
    }
  }

  f32x4* ep = (f32x4*)E + (size_t)(b * NC + c) * N_H + h4;
#pragma unroll
  for (int ch = 0; ch < 4; ch++) {
    f32x4 e;
    e[0] = s[0][ch]; e[1] = s[1][ch]; e[2] = s[2][ch]; e[3] = s[3][ch];
    ep[ch] = e;
  }
}

// Pass B: one thread per (b,h); 32 blocks x 256
__global__ __launch_bounds__(256) void chunk_scan_kernel(
    const float* __restrict__ A, const float* __restrict__ B,
    const float* __restrict__ C, const float* __restrict__ E,
    float* __restrict__ S) {
  const int idx = blockIdx.x * 256 + threadIdx.x;
  const int b = idx >> 10;
  const int h = idx & (N_H - 1);

  float a[4], bcoef[4], ccoef[4];
#pragma unroll
  for (int l = 0; l < 4; l++) {
    a[l] = 1.f / (1.f + __expf(-A[l * N_H + h]));
    bcoef[l] = B[l * N_H + h];
    ccoef[l] = C[l * N_H + h];
  }

  float m[4][4] = {};
  m[0][0] = a[0];
  m[1][0] = bcoef[1] * ccoef[0] * a[0];
  m[1][1] = a[1];
  m[2][0] = bcoef[2] * ccoef[1] * m[1][0];
  m[2][1] = bcoef[2] * ccoef[1] * a[1];
  m[2][2] = a[2];
  m[3][0] = bcoef[3] * ccoef[2] * m[2][0];
  m[3][1] = bcoef[3] * ccoef[2] * m[2][1];
  m[3][2] = bcoef[3] * ccoef[2] * a[2];
  m[3][3] = a[3];

  // P = M^LC, LC=32 -> 5 squarings (full 4x4; zeros fold at compile time)
#pragma unroll
  for (int it = 0; it < 5; it++) {
    float t[4][4];
#pragma unroll
    for (int i = 0; i < 4; i++)
#pragma unroll
      for (int j = 0; j < 4; j++) {
        float acc = 0.f;
#pragma unroll
        for (int k = 0; k < 4; k++) acc = fmaf(m[i][k], m[k][j], acc);
        t[i][j] = acc;
      }
#pragma unroll
    for (int i = 0; i < 4; i++)
#pragma unroll
      for (int j = 0; j < 4; j++) m[i][j] = t[i][j];
  }

  float s[4] = {0.f, 0.f, 0.f, 0.f};
  const f32x4* Ep = (const f32x4*)E + (size_t)b * NC * N_H + h;
  f32x4* Sp = (f32x4*)S + (size_t)b * NC * N_H + h;
#pragma unroll 4
  for (int c = 0; c < NC; c++) {
    f32x4 sv;
    sv[0] = s[0]; sv[1] = s[1]; sv[2] = s[2]; sv[3] = s[3];
    Sp[(size_t)c * N_H] = sv;
    f32x4 e = Ep[(size_t)c * N_H];
    float ns[4];
#pragma unroll
    for (int i = 0; i < 4; i++) {
      float acc = e[i];
#pragma unroll
      for (int k = 0; k < 4; k++) acc = fmaf(m[i][k], s[k], acc);
      ns[i] = acc;
    }
#pragma unroll
    for (int i = 0; i < 4; i++) s[i] = ns[i];
  }
}

// Pass C: like A but starts from exact state and writes y in place
__global__ __launch_bounds__(256) void chunk_apply_kernel(
    float* __restrict__ Y, const float* __restrict__ A,
    const float* __restrict__ B, const float* __restrict__ C,
    const float* __restrict__ D, const float* __restrict__ S) {
  const int b  = blockIdx.x / NC;
  const int c  = blockIdx.x % NC;
  const int h4 = threadIdx.x << 2;

  float a[4][4], bb[4][4], cc[4][4], dd[4][4];
#pragma unroll
  for (int l = 0; l < 4; l++) {
    f32x4 av = *(const f32x4*)(A + l * N_H + h4);
    f32x4 bv = *(const f32x4*)(B + l * N_H + h4);
    f32x4 cv = *(const f32x4*)(C + l * N_H + h4);
    f32x4 dv = *(const f32x4*)(D + l * N_H + h4);
#pragma unroll
    for (int ch = 0; ch < 4; ch++) {
      a[l][ch]  = 1.f / (1.f + __expf(-av[ch]));
      bb[l][ch] = bv[ch]; cc[l][ch] = cv[ch]; dd[l][ch] = dv[ch];
    }
  }

  float s[4][4];
  const f32x4* sp = (const f32x4*)S + (size_t)(b * NC + c) * N_H + h4;
#pragma unroll
  for (int ch = 0; ch < 4; ch++) {
    f32x4 sv = sp[ch];
    s[0][ch] = sv[0]; s[1][ch] = sv[1]; s[2][ch] = sv[2]; s[3][ch] = sv[3];
  }

  f32x4* yp = (f32x4*)(Y + ((size_t)b * T_SEQ + (size_t)c * LC) * N_H) + (h4 >> 2);
#pragma unroll 4
  for (int t = 0; t < LC; t++) {
    f32x4 xv = yp[(size_t)t * (N_H / 4)];
#pragma unroll
    for (int ch = 0; ch < 4; ch++) {
      float x = xv[ch];
#pragma unroll
      for (int l = 0; l < 4; l++) {
        s[l][ch] = fmaf(a[l][ch], s[l][ch], bb[l][ch] * x);
        x = fmaf(cc[l][ch], s[l][ch], dd[l][ch]);
      }
      xv[ch] = x;
    }
    yp[(size_t)t * (N_H / 4)] = xv;
  }
}

extern "C" void kernel_launch(void* const* d_in, const int* in_sizes, int n_in,
                              void* d_out, int out_size, void* d_ws, size_t ws_size,
                              hipStream_t stream) {
  const float* x    = (const float*)d_in[0];
  const float* W    = (const float*)d_in[1];
  const float* b_in = (const float*)d_in[2];
  const float* A    = (const float*)d_in[3];
  const float* B    = (const float*)d_in[4];
  const float* C    = (const float*)d_in[5];
  const float* bias = (const float*)d_in[6];
  float* out = (float*)d_out;

  // ws layout: xb [32 MiB bf16] then Wt [1 MiB bf16].
  // After the GEMM consumes xb, its region is reused for E (16 MiB) + S (16 MiB).
  ushort* xb = (ushort*)d_ws;
  ushort* Wt = xb + (size_t)M_TOT * K_F;
  float* E = (float*)d_ws;                                // [BT][NC][N_H][4]
  float* S = E + (size_t)BT * NC * N_H * 4;               // [BT][NC][N_H][4]

  cvt_x_kernel<<<(M_TOT * K_F) / (256 * 8), 256, 0, stream>>>(x, xb);
  trans_w_kernel<<<dim3(K_F / 32, N_H / 32), 256, 0, stream>>>(W, Wt);
  gemm_kernel<<<dim3(M_TOT / BM, N_H / BN), 256, 0, stream>>>(xb, Wt, b_in, out);
  chunk_state_kernel<<<BT * NC, 256, 0, stream>>>(out, A, B, C, bias, E);
  chunk_scan_kernel<<<(BT * N_H) / 256, 256, 0, stream>>>(A, B, C, E, S);
  chunk_apply_kernel<<<BT * NC, 256, 0, stream>>>(out, A, B, C, bias, S);
}

// Round 3
// 175.768 us; speedup vs baseline: 2.1568x; 1.0420x over previous
//
#include <hip/hip_runtime.h>
#include <hip/hip_bf16.h>
#include <stdint.h>

// Problem sizes (fixed by reference)
#define BT     8
#define T_SEQ  4096
#define K_F    512
#define N_H    1024
#define M_TOT  (BT * T_SEQ)   // 32768
#define NLAYER 4
#define LC     32             // chunk length for parallel scan
#define NC     (T_SEQ / LC)   // 128 chunks

typedef short  bf16x8 __attribute__((ext_vector_type(8)));
typedef float  f32x4  __attribute__((ext_vector_type(4)));
typedef ushort u16x8  __attribute__((ext_vector_type(8)));

// f32 -> bf16 (round-to-nearest-even)
__device__ __forceinline__ ushort f2bf(float f) {
  uint32_t u = __builtin_bit_cast(uint32_t, f);
  u += 0x7fffu + ((u >> 16) & 1u);
  return (ushort)(u >> 16);
}

// async global->LDS, 16B per lane (global_load_lds_dwordx4).
// dst must be wave-uniform base; HW writes lane*16B from it. src is per-lane.
__device__ __forceinline__ void gload16(const void* g, void* l) {
  __builtin_amdgcn_global_load_lds(
      (const __attribute__((address_space(1))) uint32_t*)g,
      (__attribute__((address_space(3))) uint32_t*)l, 16, 0, 0);
}

// ---------------- x: f32 -> bf16, 8 elems/thread ----------------
__global__ __launch_bounds__(256) void cvt_x_kernel(const float* __restrict__ x,
                                                    ushort* __restrict__ xb) {
  const int i = blockIdx.x * 256 + threadIdx.x;
  const float4* xv = (const float4*)x;
  float4 v0 = xv[2 * i + 0];
  float4 v1 = xv[2 * i + 1];
  u16x8 o;
  o[0] = f2bf(v0.x); o[1] = f2bf(v0.y); o[2] = f2bf(v0.z); o[3] = f2bf(v0.w);
  o[4] = f2bf(v1.x); o[5] = f2bf(v1.y); o[6] = f2bf(v1.z); o[7] = f2bf(v1.w);
  *((u16x8*)xb + i) = o;
}

// ---------------- W [K][N] f32 -> Wt [N][K] bf16 ----------------
__global__ __launch_bounds__(256) void trans_w_kernel(const float* __restrict__ W,
                                                      ushort* __restrict__ Wt) {
  __shared__ float tile[32][33];
  const int lx = threadIdx.x & 31;
  const int ly = threadIdx.x >> 5;
  const int k0 = blockIdx.x * 32;
  const int n0 = blockIdx.y * 32;
#pragma unroll
  for (int j = 0; j < 32; j += 8)
    tile[ly + j][lx] = W[(size_t)(k0 + ly + j) * N_H + n0 + lx];
  __syncthreads();
#pragma unroll
  for (int j = 0; j < 32; j += 8)
    Wt[(size_t)(n0 + ly + j) * K_F + k0 + lx] = f2bf(tile[lx][ly + j]);
}

// ---------------- GEMM: Y[M][N] = Xb[M][K] * Wt[N][K]^T + bias --------------
// m97 structure: 128x128 tile, BK=64, global_load_lds width=16, 2-barrier loop.
// Fragment layouts (measured, learn_hip m89/m91/m92):
//   A/B: row/col = lane&15, k = (lane>>4)*8 + i (contiguous bf16x8)
//   D:   col = lane&15,   row = (lane>>4)*4 + reg
#define BM 128
#define BN 128
#define BKK 64

__global__ __launch_bounds__(256) void gemm_kernel(const ushort* __restrict__ Xb,
                                                   const ushort* __restrict__ Wt,
                                                   const float* __restrict__ bias,
                                                   float* __restrict__ Y) {
  __shared__ ushort lsA[BM * BKK];   // [128 rows][64 k], 128B/row, 16 KiB
  __shared__ ushort lsB[BN * BKK];
  const int tid  = threadIdx.x;
  const int lane = tid & 63;
  const int wv   = tid >> 6;     // wave 0..3
  const int wr   = wv >> 1;      // wave row (0..1) -> 64 rows
  const int wc   = wv & 1;       // wave col (0..1) -> 64 cols
  const int m0   = blockIdx.x * BM;
  const int n0   = blockIdx.y * BN;

  // staging: each wave issues 4 x 1024B regions per tile.
  // region (wv*4+i): rows (wv*4+i)*8 + lane/8, col elems (lane&7)*8
  const int srow = (lane >> 3);        // 0..7 within region
  const int scol = (lane & 7) * 8;     // k-elem offset
  const ushort* gA = Xb + (size_t)m0 * K_F + scol;
  const ushort* gB = Wt + (size_t)n0 * K_F + scol;

  f32x4 acc[4][4];
#pragma unroll
  for (int i = 0; i < 4; i++)
#pragma unroll
    for (int j = 0; j < 4; j++) acc[i][j] = (f32x4)0.0f;

  const int lr = lane & 15;
  const int kg = (lane >> 4) * 8;

  for (int kt = 0; kt < K_F; kt += BKK) {
#pragma unroll
    for (int i = 0; i < 4; i++) {
      const int reg = wv * 4 + i;          // region id 0..15
      const int r   = reg * 8 + srow;      // tile row
      gload16(gA + (size_t)r * K_F + kt, &lsA[reg * 512]);
      gload16(gB + (size_t)r * K_F + kt, &lsB[reg * 512]);
    }
    __syncthreads();   // compiler drains vmcnt before barrier -> LDS tile ready

    bf16x8 af[4][2], bfr[4][2];
#pragma unroll
    for (int fm = 0; fm < 4; fm++)
#pragma unroll
      for (int kk = 0; kk < 2; kk++)
        af[fm][kk] = *(const bf16x8*)&lsA[(wr * 64 + fm * 16 + lr) * BKK + kk * 32 + kg];
#pragma unroll
    for (int fn = 0; fn < 4; fn++)
#pragma unroll
      for (int kk = 0; kk < 2; kk++)
        bfr[fn][kk] = *(const bf16x8*)&lsB[(wc * 64 + fn * 16 + lr) * BKK + kk * 32 + kg];

#pragma unroll
    for (int kk = 0; kk < 2; kk++)
#pragma unroll
      for (int fm = 0; fm < 4; fm++)
#pragma unroll
        for (int fn = 0; fn < 4; fn++)
          acc[fm][fn] = __builtin_amdgcn_mfma_f32_16x16x32_bf16(af[fm][kk], bfr[fn][kk],
                                                                acc[fm][fn], 0, 0, 0);
    __syncthreads();   // all ds_reads done before next tile overwrites
  }

  // epilogue: D col = lane&15, row = (lane>>4)*4 + i ; add bias
#pragma unroll
  for (int fn = 0; fn < 4; fn++) {
    const int col = n0 + wc * 64 + fn * 16 + lr;
    const float bv = bias[col];
#pragma unroll
    for (int fm = 0; fm < 4; fm++) {
      const int row0 = m0 + wr * 64 + fm * 16 + (lane >> 4) * 4;
#pragma unroll
      for (int i = 0; i < 4; i++)
        Y[(size_t)(row0 + i) * N_H + col] = acc[fm][fn][i] + bv;
    }
  }
}

// ============ chunked parallel scan for the 4-layer diagonal SSM ============
// State per channel h: s = (s0,s1,s2,s3) (one per layer).
// s_t = M s_{t-1} + (input/bias terms),  M lower-triangular:
//   M[0][0]=a0; M[l][l]=a_l; M[l][j<l] = b_l*c_{l-1}*M[l-1][j].
// Pass A: per-(b,chunk) local recurrence from 0 -> end state E.
// Pass B: per-(b,h) serial combine over chunks with P=M^LC -> start states S.
// Pass C: per-(b,chunk) recurrence from exact S, write y.

// Pass A: one thread handles 4 channels (float4); grid = BT*NC blocks x 256
__global__ __launch_bounds__(256) void chunk_state_kernel(
    const float* __restrict__ Y, const float* __restrict__ A,
    const float* __restrict__ B, const float* __restrict__ C,
    const float* __restrict__ D, float* __restrict__ E) {
  const int b  = blockIdx.x / NC;
  const int c  = blockIdx.x % NC;
  const int h4 = threadIdx.x << 2;

  float a[4][4], bb[4][4], cc[4][4], dd[4][4];
#pragma unroll
  for (int l = 0; l < 4; l++) {
    f32x4 av = *(const f32x4*)(A + l * N_H + h4);
    f32x4 bv = *(const f32x4*)(B + l * N_H + h4);
    f32x4 cv = *(const f32x4*)(C + l * N_H + h4);
    f32x4 dv = *(const f32x4*)(D + l * N_H + h4);
#pragma unroll
    for (int ch = 0; ch < 4; ch++) {
      a[l][ch]  = 1.f / (1.f + __expf(-av[ch]));
      bb[l][ch] = bv[ch]; cc[l][ch] = cv[ch]; dd[l][ch] = dv[ch];
    }
  }

  float s[4][4] = {};
  const f32x4* yp = (const f32x4*)(Y + ((size_t)b * T_SEQ + (size_t)c * LC) * N_H) +
                    (h4 >> 2);
#pragma unroll 4
  for (int t = 0; t < LC; t++) {
    f32x4 xv = yp[(size_t)t * (N_H / 4)];
#pragma unroll
    for (int ch = 0; ch < 4; ch++) {
      float x = xv[ch];
#pragma unroll
      for (int l = 0; l < 4; l++) {
        s[l][ch] = fmaf(a[l][ch], s[l][ch], bb[l][ch] * x);
        x = fmaf(cc[l][ch], s[l][ch], dd[l][ch]);
      }
    }
  }

  f32x4* ep = (f32x4*)E + (size_t)(b * NC + c) * N_H + h4;
#pragma unroll
  for (int ch = 0; ch < 4; ch++) {
    f32x4 e;
    e[0] = s[0][ch]; e[1] = s[1][ch]; e[2] = s[2][ch]; e[3] = s[3][ch];
    ep[ch] = e;
  }
}

// Pass B: one thread per (b,h); 32 blocks x 256
__global__ __launch_bounds__(256) void chunk_scan_kernel(
    const float* __restrict__ A, const float* __restrict__ B,
    const float* __restrict__ C, const float* __restrict__ E,
    float* __restrict__ S) {
  const int idx = blockIdx.x * 256 + threadIdx.x;
  const int b = idx >> 10;
  const int h = idx & (N_H - 1);

  float a[4], bcoef[4], ccoef[4];
#pragma unroll
  for (int l = 0; l < 4; l++) {
    a[l] = 1.f / (1.f + __expf(-A[l * N_H + h]));
    bcoef[l] = B[l * N_H + h];
    ccoef[l] = C[l * N_H + h];
  }

  float m[4][4] = {};
  m[0][0] = a[0];
  m[1][0] = bcoef[1] * ccoef[0] * a[0];
  m[1][1] = a[1];
  m[2][0] = bcoef[2] * ccoef[1] * m[1][0];
  m[2][1] = bcoef[2] * ccoef[1] * a[1];
  m[2][2] = a[2];
  m[3][0] = bcoef[3] * ccoef[2] * m[2][0];
  m[3][1] = bcoef[3] * ccoef[2] * m[2][1];
  m[3][2] = bcoef[3] * ccoef[2] * a[2];
  m[3][3] = a[3];

  // P = M^LC, LC=32 -> 5 squarings
#pragma unroll
  for (int it = 0; it < 5; it++) {
    float t[4][4];
#pragma unroll
    for (int i = 0; i < 4; i++)
#pragma unroll
      for (int j = 0; j < 4; j++) {
        float acc = 0.f;
#pragma unroll
        for (int k = 0; k < 4; k++) acc = fmaf(m[i][k], m[k][j], acc);
        t[i][j] = acc;
      }
#pragma unroll
    for (int i = 0; i < 4; i++)
#pragma unroll
      for (int j = 0; j < 4; j++) m[i][j] = t[i][j];
  }

  float s[4] = {0.f, 0.f, 0.f, 0.f};
  const f32x4* Ep = (const f32x4*)E + (size_t)b * NC * N_H + h;
  f32x4* Sp = (f32x4*)S + (size_t)b * NC * N_H + h;
#pragma unroll 4
  for (int c = 0; c < NC; c++) {
    f32x4 sv;
    sv[0] = s[0]; sv[1] = s[1]; sv[2] = s[2]; sv[3] = s[3];
    Sp[(size_t)c * N_H] = sv;
    f32x4 e = Ep[(size_t)c * N_H];
    float ns[4];
#pragma unroll
    for (int i = 0; i < 4; i++) {
      float acc = e[i];
#pragma unroll
      for (int k = 0; k < 4; k++) acc = fmaf(m[i][k], s[k], acc);
      ns[i] = acc;
    }
#pragma unroll
    for (int i = 0; i < 4; i++) s[i] = ns[i];
  }
}

// Pass C: like A but starts from exact state and writes y in place
__global__ __launch_bounds__(256) void chunk_apply_kernel(
    float* __restrict__ Y, const float* __restrict__ A,
    const float* __restrict__ B, const float* __restrict__ C,
    const float* __restrict__ D, const float* __restrict__ S) {
  const int b  = blockIdx.x / NC;
  const int c  = blockIdx.x % NC;
  const int h4 = threadIdx.x << 2;

  float a[4][4], bb[4][4], cc[4][4], dd[4][4];
#pragma unroll
  for (int l = 0; l < 4; l++) {
    f32x4 av = *(const f32x4*)(A + l * N_H + h4);
    f32x4 bv = *(const f32x4*)(B + l * N_H + h4);
    f32x4 cv = *(const f32x4*)(C + l * N_H + h4);
    f32x4 dv = *(const f32x4*)(D + l * N_H + h4);
#pragma unroll
    for (int ch = 0; ch < 4; ch++) {
      a[l][ch]  = 1.f / (1.f + __expf(-av[ch]));
      bb[l][ch] = bv[ch]; cc[l][ch] = cv[ch]; dd[l][ch] = dv[ch];
    }
  }

  float s[4][4];
  const f32x4* sp = (const f32x4*)S + (size_t)(b * NC + c) * N_H + h4;
#pragma unroll
  for (int ch = 0; ch < 4; ch++) {
    f32x4 sv = sp[ch];
    s[0][ch] = sv[0]; s[1][ch] = sv[1]; s[2][ch] = sv[2]; s[3][ch] = sv[3];
  }

  f32x4* yp = (f32x4*)(Y + ((size_t)b * T_SEQ + (size_t)c * LC) * N_H) + (h4 >> 2);
#pragma unroll 4
  for (int t = 0; t < LC; t++) {
    f32x4 xv = yp[(size_t)t * (N_H / 4)];
#pragma unroll
    for (int ch = 0; ch < 4; ch++) {
      float x = xv[ch];
#pragma unroll
      for (int l = 0; l < 4; l++) {
        s[l][ch] = fmaf(a[l][ch], s[l][ch], bb[l][ch] * x);
        x = fmaf(cc[l][ch], s[l][ch], dd[l][ch]);
      }
      xv[ch] = x;
    }
    yp[(size_t)t * (N_H / 4)] = xv;
  }
}

extern "C" void kernel_launch(void* const* d_in, const int* in_sizes, int n_in,
                              void* d_out, int out_size, void* d_ws, size_t ws_size,
                              hipStream_t stream) {
  const float* x    = (const float*)d_in[0];
  const float* W    = (const float*)d_in[1];
  const float* b_in = (const float*)d_in[2];
  const float* A    = (const float*)d_in[3];
  const float* B    = (const float*)d_in[4];
  const float* C    = (const float*)d_in[5];
  const float* bias = (const float*)d_in[6];
  float* out = (float*)d_out;

  // ws layout: xb [32 MiB bf16] then Wt [1 MiB bf16].
  // After the GEMM consumes xb, its region is reused for E (16 MiB) + S (16 MiB).
  ushort* xb = (ushort*)d_ws;
  ushort* Wt = xb + (size_t)M_TOT * K_F;
  float* E = (float*)d_ws;                                // [BT][NC][N_H][4]
  float* S = E + (size_t)BT * NC * N_H * 4;               // [BT][NC][N_H][4]

  cvt_x_kernel<<<(M_TOT * K_F) / (256 * 8), 256, 0, stream>>>(x, xb);
  trans_w_kernel<<<dim3(K_F / 32, N_H / 32), 256, 0, stream>>>(W, Wt);
  gemm_kernel<<<dim3(M_TOT / BM, N_H / BN), 256, 0, stream>>>(xb, Wt, b_in, out);
  chunk_state_kernel<<<BT * NC, 256, 0, stream>>>(out, A, B, C, bias, E);
  chunk_scan_kernel<<<(BT * N_H) / 256, 256, 0, stream>>>(A, B, C, E, S);
  chunk_apply_kernel<<<BT * NC, 256, 0, stream>>>(out, A, B, C, bias, S);
}

// Round 4
// 171.151 us; speedup vs baseline: 2.2150x; 1.0270x over previous
//
#include <hip/hip_runtime.h>
#include <hip/hip_bf16.h>
#include <stdint.h>

// Problem sizes (fixed by reference)
#define BT     8
#define T_SEQ  4096
#define K_F    512
#define N_H    1024
#define M_TOT  (BT * T_SEQ)   // 32768
#define NLAYER 4
#define LC     32             // chunk length for parallel scan
#define NC     (T_SEQ / LC)   // 128 chunks

typedef short  bf16x8 __attribute__((ext_vector_type(8)));
typedef float  f32x4  __attribute__((ext_vector_type(4)));
typedef ushort u16x8  __attribute__((ext_vector_type(8)));
typedef ushort u16x4  __attribute__((ext_vector_type(4)));

// f32 -> bf16 (round-to-nearest-even)
__device__ __forceinline__ ushort f2bf(float f) {
  uint32_t u = __builtin_bit_cast(uint32_t, f);
  u += 0x7fffu + ((u >> 16) & 1u);
  return (ushort)(u >> 16);
}
__device__ __forceinline__ float bf2f(ushort u) {
  uint32_t x = (uint32_t)u << 16;
  return __builtin_bit_cast(float, x);
}

// async global->LDS, 16B per lane (global_load_lds_dwordx4).
__device__ __forceinline__ void gload16(const void* g, void* l) {
  __builtin_amdgcn_global_load_lds(
      (const __attribute__((address_space(1))) uint32_t*)g,
      (__attribute__((address_space(3))) uint32_t*)l, 16, 0, 0);
}

// ---------------- x: f32 -> bf16, 8 elems/thread ----------------
__global__ __launch_bounds__(256) void cvt_x_kernel(const float* __restrict__ x,
                                                    ushort* __restrict__ xb) {
  const int i = blockIdx.x * 256 + threadIdx.x;
  const float4* xv = (const float4*)x;
  float4 v0 = xv[2 * i + 0];
  float4 v1 = xv[2 * i + 1];
  u16x8 o;
  o[0] = f2bf(v0.x); o[1] = f2bf(v0.y); o[2] = f2bf(v0.z); o[3] = f2bf(v0.w);
  o[4] = f2bf(v1.x); o[5] = f2bf(v1.y); o[6] = f2bf(v1.z); o[7] = f2bf(v1.w);
  *((u16x8*)xb + i) = o;
}

// ---------------- W [K][N] f32 -> Wt [N][K] bf16 ----------------
__global__ __launch_bounds__(256) void trans_w_kernel(const float* __restrict__ W,
                                                      ushort* __restrict__ Wt) {
  __shared__ float tile[32][33];
  const int lx = threadIdx.x & 31;
  const int ly = threadIdx.x >> 5;
  const int k0 = blockIdx.x * 32;
  const int n0 = blockIdx.y * 32;
#pragma unroll
  for (int j = 0; j < 32; j += 8)
    tile[ly + j][lx] = W[(size_t)(k0 + ly + j) * N_H + n0 + lx];
  __syncthreads();
#pragma unroll
  for (int j = 0; j < 32; j += 8)
    Wt[(size_t)(n0 + ly + j) * K_F + k0 + lx] = f2bf(tile[lx][ly + j]);
}

// ---------------- GEMM: Yb[M][N] = bf16(Xb[M][K] * Wt[N][K]^T + bias) -------
// m97 structure: 128x128 tile, BK=64, global_load_lds width=16, 2-barrier loop.
#define BM 128
#define BN 128
#define BKK 64

__global__ __launch_bounds__(256) void gemm_kernel(const ushort* __restrict__ Xb,
                                                   const ushort* __restrict__ Wt,
                                                   const float* __restrict__ bias,
                                                   ushort* __restrict__ Yb) {
  __shared__ ushort lsA[BM * BKK];   // [128 rows][64 k], 16 KiB
  __shared__ ushort lsB[BN * BKK];
  const int tid  = threadIdx.x;
  const int lane = tid & 63;
  const int wv   = tid >> 6;     // wave 0..3
  const int wr   = wv >> 1;      // wave row (0..1) -> 64 rows
  const int wc   = wv & 1;       // wave col (0..1) -> 64 cols
  const int m0   = blockIdx.x * BM;
  const int n0   = blockIdx.y * BN;

  const int srow = (lane >> 3);        // 0..7 within region
  const int scol = (lane & 7) * 8;     // k-elem offset
  const ushort* gA = Xb + (size_t)m0 * K_F + scol;
  const ushort* gB = Wt + (size_t)n0 * K_F + scol;

  f32x4 acc[4][4];
#pragma unroll
  for (int i = 0; i < 4; i++)
#pragma unroll
    for (int j = 0; j < 4; j++) acc[i][j] = (f32x4)0.0f;

  const int lr = lane & 15;
  const int kg = (lane >> 4) * 8;

  for (int kt = 0; kt < K_F; kt += BKK) {
#pragma unroll
    for (int i = 0; i < 4; i++) {
      const int reg = wv * 4 + i;          // region id 0..15
      const int r   = reg * 8 + srow;      // tile row
      gload16(gA + (size_t)r * K_F + kt, &lsA[reg * 512]);
      gload16(gB + (size_t)r * K_F + kt, &lsB[reg * 512]);
    }
    __syncthreads();

    bf16x8 af[4][2], bfr[4][2];
#pragma unroll
    for (int fm = 0; fm < 4; fm++)
#pragma unroll
      for (int kk = 0; kk < 2; kk++)
        af[fm][kk] = *(const bf16x8*)&lsA[(wr * 64 + fm * 16 + lr) * BKK + kk * 32 + kg];
#pragma unroll
    for (int fn = 0; fn < 4; fn++)
#pragma unroll
      for (int kk = 0; kk < 2; kk++)
        bfr[fn][kk] = *(const bf16x8*)&lsB[(wc * 64 + fn * 16 + lr) * BKK + kk * 32 + kg];

#pragma unroll
    for (int kk = 0; kk < 2; kk++)
#pragma unroll
      for (int fm = 0; fm < 4; fm++)
#pragma unroll
        for (int fn = 0; fn < 4; fn++)
          acc[fm][fn] = __builtin_amdgcn_mfma_f32_16x16x32_bf16(af[fm][kk], bfr[fn][kk],
                                                                acc[fm][fn], 0, 0, 0);
    __syncthreads();
  }

  // epilogue: D col = lane&15, row = (lane>>4)*4 + i ; add bias, store bf16
#pragma unroll
  for (int fn = 0; fn < 4; fn++) {
    const int col = n0 + wc * 64 + fn * 16 + lr;
    const float bv = bias[col];
#pragma unroll
    for (int fm = 0; fm < 4; fm++) {
      const int row0 = m0 + wr * 64 + fm * 16 + (lane >> 4) * 4;
#pragma unroll
      for (int i = 0; i < 4; i++)
        Yb[(size_t)(row0 + i) * N_H + col] = f2bf(acc[fm][fn][i] + bv);
    }
  }
}

// ============ chunked parallel scan for the 4-layer diagonal SSM ============
// Pass A: per-(b,chunk) local recurrence from 0 -> end state E (reads bf16 Y).
// Pass B: per-(b,h) serial combine over chunks with P=M^LC -> start states S.
// Pass C: per-(b,chunk) recurrence from exact S (reads bf16 Y), writes f32 out.

// Pass A: one thread handles 4 channels; grid = BT*NC blocks x 256
__global__ __launch_bounds__(256) void chunk_state_kernel(
    const ushort* __restrict__ Yb, const float* __restrict__ A,
    const float* __restrict__ B, const float* __restrict__ C,
    const float* __restrict__ D, float* __restrict__ E) {
  const int b  = blockIdx.x / NC;
  const int c  = blockIdx.x % NC;
  const int h4 = threadIdx.x << 2;

  float a[4][4], bb[4][4], cc[4][4], dd[4][4];
#pragma unroll
  for (int l = 0; l < 4; l++) {
    f32x4 av = *(const f32x4*)(A + l * N_H + h4);
    f32x4 bv = *(const f32x4*)(B + l * N_H + h4);
    f32x4 cv = *(const f32x4*)(C + l * N_H + h4);
    f32x4 dv = *(const f32x4*)(D + l * N_H + h4);
#pragma unroll
    for (int ch = 0; ch < 4; ch++) {
      a[l][ch]  = 1.f / (1.f + __expf(-av[ch]));
      bb[l][ch] = bv[ch]; cc[l][ch] = cv[ch]; dd[l][ch] = dv[ch];
    }
  }

  float s[4][4] = {};
  const ushort* ybase = Yb + ((size_t)b * T_SEQ + (size_t)c * LC) * N_H + h4;
#pragma unroll 4
  for (int t = 0; t < LC; t++) {
    u16x4 xv = *(const u16x4*)(ybase + (size_t)t * N_H);
#pragma unroll
    for (int ch = 0; ch < 4; ch++) {
      float x = bf2f(xv[ch]);
#pragma unroll
      for (int l = 0; l < 4; l++) {
        s[l][ch] = fmaf(a[l][ch], s[l][ch], bb[l][ch] * x);
        x = fmaf(cc[l][ch], s[l][ch], dd[l][ch]);
      }
    }
  }

  f32x4* ep = (f32x4*)E + (size_t)(b * NC + c) * N_H + h4;
#pragma unroll
  for (int ch = 0; ch < 4; ch++) {
    f32x4 e;
    e[0] = s[0][ch]; e[1] = s[1][ch]; e[2] = s[2][ch]; e[3] = s[3][ch];
    ep[ch] = e;
  }
}

// Pass B: one thread per (b,h); 32 blocks x 256
__global__ __launch_bounds__(256) void chunk_scan_kernel(
    const float* __restrict__ A, const float* __restrict__ B,
    const float* __restrict__ C, const float* __restrict__ E,
    float* __restrict__ S) {
  const int idx = blockIdx.x * 256 + threadIdx.x;
  const int b = idx >> 10;
  const int h = idx & (N_H - 1);

  float a[4], bcoef[4], ccoef[4];
#pragma unroll
  for (int l = 0; l < 4; l++) {
    a[l] = 1.f / (1.f + __expf(-A[l * N_H + h]));
    bcoef[l] = B[l * N_H + h];
    ccoef[l] = C[l * N_H + h];
  }

  float m[4][4] = {};
  m[0][0] = a[0];
  m[1][0] = bcoef[1] * ccoef[0] * a[0];
  m[1][1] = a[1];
  m[2][0] = bcoef[2] * ccoef[1] * m[1][0];
  m[2][1] = bcoef[2] * ccoef[1] * a[1];
  m[2][2] = a[2];
  m[3][0] = bcoef[3] * ccoef[2] * m[2][0];
  m[3][1] = bcoef[3] * ccoef[2] * m[2][1];
  m[3][2] = bcoef[3] * ccoef[2] * a[2];
  m[3][3] = a[3];

  // P = M^LC, LC=32 -> 5 squarings
#pragma unroll
  for (int it = 0; it < 5; it++) {
    float t[4][4];
#pragma unroll
    for (int i = 0; i < 4; i++)
#pragma unroll
      for (int j = 0; j < 4; j++) {
        float acc = 0.f;
#pragma unroll
        for (int k = 0; k < 4; k++) acc = fmaf(m[i][k], m[k][j], acc);
        t[i][j] = acc;
      }
#pragma unroll
    for (int i = 0; i < 4; i++)
#pragma unroll
      for (int j = 0; j < 4; j++) m[i][j] = t[i][j];
  }

  float s[4] = {0.f, 0.f, 0.f, 0.f};
  const f32x4* Ep = (const f32x4*)E + (size_t)b * NC * N_H + h;
  f32x4* Sp = (f32x4*)S + (size_t)b * NC * N_H + h;
#pragma unroll 4
  for (int c = 0; c < NC; c++) {
    f32x4 sv;
    sv[0] = s[0]; sv[1] = s[1]; sv[2] = s[2]; sv[3] = s[3];
    Sp[(size_t)c * N_H] = sv;
    f32x4 e = Ep[(size_t)c * N_H];
    float ns[4];
#pragma unroll
    for (int i = 0; i < 4; i++) {
      float acc = e[i];
#pragma unroll
      for (int k = 0; k < 4; k++) acc = fmaf(m[i][k], s[k], acc);
      ns[i] = acc;
    }
#pragma unroll
    for (int i = 0; i < 4; i++) s[i] = ns[i];
  }
}

// Pass C: recurrence from exact start state; reads bf16 Y, writes f32 out
__global__ __launch_bounds__(256) void chunk_apply_kernel(
    const ushort* __restrict__ Yb, float* __restrict__ out,
    const float* __restrict__ A, const float* __restrict__ B,
    const float* __restrict__ C, const float* __restrict__ D,
    const float* __restrict__ S) {
  const int b  = blockIdx.x / NC;
  const int c  = blockIdx.x % NC;
  const int h4 = threadIdx.x << 2;

  float a[4][4], bb[4][4], cc[4][4], dd[4][4];
#pragma unroll
  for (int l = 0; l < 4; l++) {
    f32x4 av = *(const f32x4*)(A + l * N_H + h4);
    f32x4 bv = *(const f32x4*)(B + l * N_H + h4);
    f32x4 cv = *(const f32x4*)(C + l * N_H + h4);
    f32x4 dv = *(const f32x4*)(D + l * N_H + h4);
#pragma unroll
    for (int ch = 0; ch < 4; ch++) {
      a[l][ch]  = 1.f / (1.f + __expf(-av[ch]));
      bb[l][ch] = bv[ch]; cc[l][ch] = cv[ch]; dd[l][ch] = dv[ch];
    }
  }

  float s[4][4];
  const f32x4* sp = (const f32x4*)S + (size_t)(b * NC + c) * N_H + h4;
#pragma unroll
  for (int ch = 0; ch < 4; ch++) {
    f32x4 sv = sp[ch];
    s[0][ch] = sv[0]; s[1][ch] = sv[1]; s[2][ch] = sv[2]; s[3][ch] = sv[3];
  }

  const ushort* ybase = Yb + ((size_t)b * T_SEQ + (size_t)c * LC) * N_H + h4;
  f32x4* op = (f32x4*)(out + ((size_t)b * T_SEQ + (size_t)c * LC) * N_H) + (h4 >> 2);
#pragma unroll 4
  for (int t = 0; t < LC; t++) {
    u16x4 xv = *(const u16x4*)(ybase + (size_t)t * N_H);
    f32x4 ov;
#pragma unroll
    for (int ch = 0; ch < 4; ch++) {
      float x = bf2f(xv[ch]);
#pragma unroll
      for (int l = 0; l < 4; l++) {
        s[l][ch] = fmaf(a[l][ch], s[l][ch], bb[l][ch] * x);
        x = fmaf(cc[l][ch], s[l][ch], dd[l][ch]);
      }
      ov[ch] = x;
    }
    op[(size_t)t * (N_H / 4)] = ov;
  }
}

extern "C" void kernel_launch(void* const* d_in, const int* in_sizes, int n_in,
                              void* d_out, int out_size, void* d_ws, size_t ws_size,
                              hipStream_t stream) {
  const float* x    = (const float*)d_in[0];
  const float* W    = (const float*)d_in[1];
  const float* b_in = (const float*)d_in[2];
  const float* A    = (const float*)d_in[3];
  const float* B    = (const float*)d_in[4];
  const float* C    = (const float*)d_in[5];
  const float* bias = (const float*)d_in[6];
  float* out = (float*)d_out;

  // ws layout (512 MiB available):
  //   xb  [0,   32 MiB)  bf16 x
  //   Wt  [32,  33 MiB)  bf16 W^T
  //   Yb  [40, 104 MiB)  bf16 intermediate Y
  //   E   [112,129 MiB)  f32 chunk end states
  //   S   [129,146 MiB)  f32 chunk start states
  char* wsb = (char*)d_ws;
  ushort* xb = (ushort*)wsb;
  ushort* Wt = (ushort*)(wsb + (size_t)33 * 1024 * 1024 - (size_t)N_H * K_F * 2);
  ushort* Yb = (ushort*)(wsb + (size_t)40 * 1024 * 1024);
  float*  E  = (float*)(wsb + (size_t)112 * 1024 * 1024);
  float*  S  = E + (size_t)BT * NC * N_H * 4;

  cvt_x_kernel<<<(M_TOT * K_F) / (256 * 8), 256, 0, stream>>>(x, xb);
  trans_w_kernel<<<dim3(K_F / 32, N_H / 32), 256, 0, stream>>>(W, Wt);
  gemm_kernel<<<dim3(M_TOT / BM, N_H / BN), 256, 0, stream>>>(xb, Wt, b_in, Yb);
  chunk_state_kernel<<<BT * NC, 256, 0, stream>>>(Yb, A, B, C, bias, E);
  chunk_scan_kernel<<<(BT * N_H) / 256, 256, 0, stream>>>(A, B, C, E, S);
  chunk_apply_kernel<<<BT * NC, 256, 0, stream>>>(Yb, out, A, B, C, bias, S);
}